// Round 2
// baseline (794.579 us; speedup 1.0000x reference)
//
#include <hip/hip_runtime.h>

typedef unsigned short ushort_t;
typedef unsigned int uint_t;
typedef __attribute__((ext_vector_type(8))) short short8;
typedef __attribute__((ext_vector_type(4))) short short4v;
typedef __attribute__((ext_vector_type(4))) float floatx4;

__device__ __forceinline__ float bf2f(ushort_t u){
    union { uint_t i; float f; } c; c.i = ((uint_t)u) << 16; return c.f;
}
__device__ __forceinline__ ushort_t f2bf(float x){
    union { float f; uint_t i; } c; c.f = x;
    uint_t i = c.i;
    return (ushort_t)((i + 0x7fffu + ((i >> 16) & 1u)) >> 16);
}
// fast pack of 2 fp32 -> 2 bf16 (round-half-up): 2 adds + v_perm
__device__ __forceinline__ uint_t cvt2fast(float a, float b){
    union { float f; uint_t i; } ca, cb; ca.f = a; cb.f = b;
    uint_t ia = ca.i + 0x8000u, ib = cb.i + 0x8000u;
    return __builtin_amdgcn_perm(ib, ia, 0x07060302u);
}
__device__ __forceinline__ float relu_f(float x){ return fmaxf(x, 0.0f); }
__device__ __forceinline__ float sigmoid_f(float x){ return 1.0f / (1.0f + __expf(-x)); }

#define NT 2048
#define TT 64

// ---------------- prep: Wihb[j][k] = bf16(Wih[j][k]), k<512 ----------------
__global__ __launch_bounds__(256) void prep_kernel(
    const float* __restrict__ Wih, ushort_t* __restrict__ Wihb)
{
    int i = blockIdx.x * 256 + threadIdx.x;   // 262144
    int j = i >> 9, k = i & 511;
    Wihb[i] = f2bf(Wih[j * 532 + k]);
}

// ---------------- prep conv weights: W1b[8][32oc][32k], W2b[16][64oc][32ic], W3b[9][64oc][64ic] ----------------
__global__ __launch_bounds__(256) void prep_convw_kernel(
    const float* __restrict__ W1, const float* __restrict__ W2,
    const float* __restrict__ W3, ushort_t* __restrict__ W1b,
    ushort_t* __restrict__ W2b, ushort_t* __restrict__ W3b)
{
    int i = blockIdx.x * 256 + threadIdx.x;   // 77824 total
    if (i < 8192) {                           // W1b: k = kx*3+ic (24 real, pad 8 zeros)
        int ky = i >> 10, oc = (i >> 5) & 31, k = i & 31;
        float v = 0.0f;
        if (k < 24) { int kx = k / 3, ic = k % 3; v = W1[((ky * 8 + kx) * 3 + ic) * 32 + oc]; }
        W1b[i] = f2bf(v);
        return;
    }
    i -= 8192;
    if (i < 32768) {                          // W2b[kk][oc][ic]
        int kk = i >> 11, oc = (i >> 5) & 63, ic = i & 31;
        W2b[i] = f2bf(W2[(kk * 32 + ic) * 64 + oc]);
        return;
    }
    i -= 32768;
    if (i < 36864) {                          // W3b[p][oc][ic]
        int p = i >> 12, oc = (i >> 6) & 63, ic = i & 63;
        W3b[i] = f2bf(W3[(p * 64 + ic) * 64 + oc]);
    }
}

// ---------------- wfct: Wfc[3136][512] f32 -> WfcT[512][3136] bf16 ----------------
__global__ __launch_bounds__(256) void wfct_kernel(
    const float* __restrict__ Wfc, ushort_t* __restrict__ WfcT)
{
    __shared__ ushort_t t_s[64][65];
    int kb = blockIdx.x % 49, jb = blockIdx.x / 49;   // 49*8 blocks
    int k0 = kb * 64, j0 = jb * 64;
    int jj = threadIdx.x & 63, i4 = threadIdx.x >> 6;
    for (int rr = i4; rr < 64; rr += 4)
        t_s[rr][jj] = f2bf(Wfc[(size_t)(k0 + rr) * 512 + j0 + jj]);
    __syncthreads();
    for (int rr = i4; rr < 64; rr += 4)
        WfcT[(size_t)(j0 + rr) * 3136 + k0 + jj] = t_s[jj][rr];
}

// ---------------- fused convs via MFMA, block per sample ----------------
// 512 threads (8 waves) per sample: 4 blocks/CU x 8 waves = 32 waves/CU (100% occ,
// requires VGPR<=64 via launch_bounds; 256-thread build measured 60). LDS layouts
// swizzled for conflict-free 16B ds_read_b128 fragment loads:
//   c1: x-parity planes [20y][10x'][32ic], 64B/pos, chunk ^= pos&3
//   c2: [81pos][64ic], 128B/pos, chunk ^= pos&7
__global__ __launch_bounds__(512, 8) void convs_mfma(
    const float* __restrict__ img,
    const ushort_t* __restrict__ W1b, const float* __restrict__ b1,
    const ushort_t* __restrict__ W2b, const float* __restrict__ b2,
    const ushort_t* __restrict__ W3b, const float* __restrict__ b3,
    ushort_t* __restrict__ out3)
{
    __shared__ __align__(16) ushort_t c1e[200 * 32];   // 12,800 B (even x)
    __shared__ __align__(16) ushort_t c1o[200 * 32];   // 12,800 B (odd x)
    __shared__ __align__(16) ushort_t c2_s[81 * 64];   // 10,368 B

    int n = blockIdx.x, tid = threadIdx.x;
    int w = tid >> 6, lane = tid & 63;
    int r = lane & 15, q = lane >> 4;

    // ---- conv1: 20x20x32, k=8 s=4; K=32 (kx*3+ic, B-rows zero-padded 24..31) ----
    // wave = px-phase; each wave computes BOTH 16-oc tiles from one A-fragment
    {
        short8 bf0[8], bf1[8];
        #pragma unroll
        for (int ky = 0; ky < 8; ky++) {
            bf0[ky] = *(const short8*)(W1b + (ky * 32 +      r) * 32 + q * 8);
            bf1[ky] = *(const short8*)(W1b + (ky * 32 + 16 + r) * 32 + q * 8);
        }
        float bb0 = b1[r], bb1 = b1[16 + r];
        const float* abase = img + (size_t)n * 21168;
        for (int t = w; t < 25; t += 8) {
            int pxa = t * 16 + r;
            int oy = pxa / 20, ox = pxa % 20;
            floatx4 acc0 = {0.f, 0.f, 0.f, 0.f}, acc1 = {0.f, 0.f, 0.f, 0.f};
            #pragma unroll
            for (int ky = 0; ky < 8; ky++) {
                short8 a = {0,0,0,0,0,0,0,0};
                if (q < 3) {
                    const float* p = abase + ((oy * 4 + ky) * 84 + ox * 4) * 3 + q * 8;
                    float4 f0 = *(const float4*)p;
                    float4 f1 = *(const float4*)(p + 4);
                    union { uint_t u[4]; short8 s; } pk;
                    pk.u[0] = cvt2fast(f0.x, f0.y);
                    pk.u[1] = cvt2fast(f0.z, f0.w);
                    pk.u[2] = cvt2fast(f1.x, f1.y);
                    pk.u[3] = cvt2fast(f1.z, f1.w);
                    a = pk.s;
                }
                acc0 = __builtin_amdgcn_mfma_f32_16x16x32_bf16(a, bf0[ky], acc0, 0, 0, 0);
                acc1 = __builtin_amdgcn_mfma_f32_16x16x32_bf16(a, bf1[ky], acc1, 0, 0, 0);
            }
            int pxs = t * 16 + q * 4;
            #pragma unroll
            for (int i = 0; i < 4; i++) {
                int px = pxs + i;
                int y = px / 20, x = px % 20;
                int pos = y * 10 + (x >> 1);
                ushort_t* pl = (i & 1) ? c1o : c1e;   // x parity == i parity (t*16, q*4 even)
                int base = pos * 32 + (r & 7);
                pl[base + ((((r >> 3)    ) ^ (pos & 3)) << 3)] = f2bf(relu_f(acc0[i] + bb0));
                pl[base + (((2 + (r >> 3)) ^ (pos & 3)) << 3)] = f2bf(relu_f(acc1[i] + bb1));
            }
        }
    }
    __syncthreads();

    // ---- conv2: 9x9x64, k=4 s=2; 16 pos x K=32; wave = (oc-tile, t-half) ----
    {
        int oct = w & 3, th = w >> 2;
        short8 bfr[16];
        #pragma unroll
        for (int kk = 0; kk < 16; kk++)
            bfr[kk] = *(const short8*)(W2b + (kk * 64 + oct * 16 + r) * 32 + q * 8);
        float bb = b2[oct * 16 + r];
        for (int t = th; t < 6; t += 2) {
            int pxa = min(t * 16 + r, 80);
            int oy = pxa / 9, ox = pxa % 9;
            floatx4 acc = {0.f, 0.f, 0.f, 0.f};
            #pragma unroll
            for (int ky = 0; ky < 4; ky++) {
                int pos0 = (oy * 2 + ky) * 10 + ox;
                #pragma unroll
                for (int kxh = 0; kxh < 2; kxh++) {   // kx = 2*kxh (even plane), 2*kxh+1 (odd)
                    int pos = pos0 + kxh;
                    int idx = pos * 32 + ((q ^ (pos & 3)) << 3);
                    short8 ae = *(const short8*)(c1e + idx);
                    short8 ao = *(const short8*)(c1o + idx);
                    acc = __builtin_amdgcn_mfma_f32_16x16x32_bf16(ae, bfr[ky * 4 + kxh * 2],     acc, 0, 0, 0);
                    acc = __builtin_amdgcn_mfma_f32_16x16x32_bf16(ao, bfr[ky * 4 + kxh * 2 + 1], acc, 0, 0, 0);
                }
            }
            #pragma unroll
            for (int i = 0; i < 4; i++) {
                int px = t * 16 + q * 4 + i;
                if (px < 81) {
                    int oc = oct * 16 + r;
                    c2_s[px * 64 + ((((oc >> 3)) ^ (px & 7)) << 3) + (oc & 7)] = f2bf(relu_f(acc[i] + bb));
                }
            }
        }
    }
    __syncthreads();

    // ---- conv3: 7x7x64, k=3 s=1; 9 pos x K=64 (2 chunks); wave = (oc-tile, t-half) ----
    {
        int oct = w & 3, th = w >> 2;
        short8 bfr[18];
        #pragma unroll
        for (int p = 0; p < 9; p++) {
            #pragma unroll
            for (int h = 0; h < 2; h++)
                bfr[p * 2 + h] = *(const short8*)(W3b + (p * 64 + oct * 16 + r) * 64 + h * 32 + q * 8);
        }
        float bb = b3[oct * 16 + r];
        for (int t = th; t < 4; t += 2) {
            int pxa = min(t * 16 + r, 48);
            int oy = pxa / 7, ox = pxa % 7;
            floatx4 acc = {0.f, 0.f, 0.f, 0.f};
            #pragma unroll
            for (int ky = 0; ky < 3; ky++) {
                #pragma unroll
                for (int kx = 0; kx < 3; kx++) {
                    int qin = (oy + ky) * 9 + ox + kx;
                    int bidx = qin * 64;
                    int s = qin & 7;
                    short8 a0 = *(const short8*)(c2_s + bidx + ((q ^ s) << 3));
                    short8 a1 = *(const short8*)(c2_s + bidx + (((4 + q) ^ s) << 3));
                    acc = __builtin_amdgcn_mfma_f32_16x16x32_bf16(a0, bfr[(ky * 3 + kx) * 2],     acc, 0, 0, 0);
                    acc = __builtin_amdgcn_mfma_f32_16x16x32_bf16(a1, bfr[(ky * 3 + kx) * 2 + 1], acc, 0, 0, 0);
                }
            }
            #pragma unroll
            for (int i = 0; i < 4; i++) {
                int px = t * 16 + q * 4 + i;
                if (px < 49)
                    out3[(size_t)n * 3136 + px * 64 + oct * 16 + r] = f2bf(relu_f(acc[i] + bb));
            }
        }
    }
}

// ---------------- FC via MFMA: feat[2048][512] = relu(out3 @ Wfc + bfc) ----------------
__global__ __launch_bounds__(256) void fc_mfma_kernel(
    const ushort_t* __restrict__ A, const ushort_t* __restrict__ BT,
    const float* __restrict__ bfc, ushort_t* __restrict__ feat)
{
    int mb = blockIdx.x & 63, nb = blockIdx.x >> 6;   // 64 x 8
    int tid = threadIdx.x;
    int w = tid >> 6, lane = tid & 63;
    int r = lane & 15, q = lane >> 4;
    int m0 = mb * 32 + (w & 1) * 16;
    int n0 = nb * 64 + (w >> 1) * 32;
    const ushort_t* arow  = A  + (size_t)(m0 + r) * 3136 + q * 8;
    const ushort_t* brow0 = BT + (size_t)(n0 + r) * 3136 + q * 8;
    const ushort_t* brow1 = BT + (size_t)(n0 + 16 + r) * 3136 + q * 8;
    floatx4 acc0 = {0.f, 0.f, 0.f, 0.f}, acc1 = {0.f, 0.f, 0.f, 0.f};
    short8 a  = *(const short8*)arow;
    short8 b0 = *(const short8*)brow0;
    short8 b1 = *(const short8*)brow1;
    for (int kk = 1; kk < 98; kk++) {
        short8 an  = *(const short8*)(arow  + kk * 32);
        short8 b0n = *(const short8*)(brow0 + kk * 32);
        short8 b1n = *(const short8*)(brow1 + kk * 32);
        acc0 = __builtin_amdgcn_mfma_f32_16x16x32_bf16(a, b0, acc0, 0, 0, 0);
        acc1 = __builtin_amdgcn_mfma_f32_16x16x32_bf16(a, b1, acc1, 0, 0, 0);
        a = an; b0 = b0n; b1 = b1n;
    }
    acc0 = __builtin_amdgcn_mfma_f32_16x16x32_bf16(a, b0, acc0, 0, 0, 0);
    acc1 = __builtin_amdgcn_mfma_f32_16x16x32_bf16(a, b1, acc1, 0, 0, 0);
    int c0 = n0 + r, c1 = n0 + 16 + r;
    float bb0 = bfc[c0], bb1 = bfc[c1];
    #pragma unroll
    for (int i = 0; i < 4; i++) {
        int row = m0 + q * 4 + i;
        feat[(size_t)row * 512 + c0] = f2bf(relu_f(acc0[i] + bb0));
        feat[(size_t)row * 512 + c1] = f2bf(relu_f(acc1[i] + bb1));
    }
}

// ---------------- gates via MFMA: gx[2048][512] = feat @ Wih[:,:512]^T + onehot + bias ----------------
__global__ __launch_bounds__(256) void gates_mfma_kernel(
    const ushort_t* __restrict__ A, const ushort_t* __restrict__ Wihb,
    const float* __restrict__ Wih, const float* __restrict__ bih,
    const float* __restrict__ bhh, const int* __restrict__ pos,
    float* __restrict__ gx)
{
    int mb = blockIdx.x & 63, nb = blockIdx.x >> 6;   // 64 x 8
    int tid = threadIdx.x;
    int w = tid >> 6, lane = tid & 63;
    int r = lane & 15, q = lane >> 4;
    int m0 = mb * 32 + (w & 1) * 16;
    int n0 = nb * 64 + (w >> 1) * 32;
    const ushort_t* arow  = A    + (size_t)(m0 + r) * 512 + q * 8;
    const ushort_t* brow0 = Wihb + (size_t)(n0 + r) * 512 + q * 8;
    const ushort_t* brow1 = Wihb + (size_t)(n0 + 16 + r) * 512 + q * 8;
    floatx4 acc0 = {0.f, 0.f, 0.f, 0.f}, acc1 = {0.f, 0.f, 0.f, 0.f};
    short8 a  = *(const short8*)arow;
    short8 b0 = *(const short8*)brow0;
    short8 b1 = *(const short8*)brow1;
    for (int kk = 1; kk < 16; kk++) {
        short8 an  = *(const short8*)(arow  + kk * 32);
        short8 b0n = *(const short8*)(brow0 + kk * 32);
        short8 b1n = *(const short8*)(brow1 + kk * 32);
        acc0 = __builtin_amdgcn_mfma_f32_16x16x32_bf16(a, b0, acc0, 0, 0, 0);
        acc1 = __builtin_amdgcn_mfma_f32_16x16x32_bf16(a, b1, acc1, 0, 0, 0);
        a = an; b0 = b0n; b1 = b1n;
    }
    acc0 = __builtin_amdgcn_mfma_f32_16x16x32_bf16(a, b0, acc0, 0, 0, 0);
    acc1 = __builtin_amdgcn_mfma_f32_16x16x32_bf16(a, b1, acc1, 0, 0, 0);
    int j0 = n0 + r, j1 = n0 + 16 + r;
    float bias0 = bih[j0] + bhh[j0];
    float bias1 = bih[j1] + bhh[j1];
    #pragma unroll
    for (int i = 0; i < 4; i++) {
        int row = m0 + q * 4 + i;
        int p0 = pos[2 * row], p1 = pos[2 * row + 1];
        float oh0 = Wih[(size_t)j0 * 532 + 512 + p0] + Wih[(size_t)j0 * 532 + 522 + p1];
        float oh1 = Wih[(size_t)j1 * 532 + 512 + p0] + Wih[(size_t)j1 * 532 + 522 + p1];
        gx[(size_t)row * 512 + j0] = acc0[i] + bias0 + oh0;
        gx[(size_t)row * 512 + j1] = acc1[i] + bias1 + oh1;
    }
}

// ---------------- LSTM: 32 independent blocks (one per batch element) ----------------
__global__ __launch_bounds__(512, 2) void lstm_kernel(
    const float* __restrict__ gx, const float* __restrict__ Whh,
    const int* __restrict__ done, const float* __restrict__ h0,
    const float* __restrict__ c0, ushort_t* __restrict__ hs,
    float* __restrict__ out)
{
    __shared__ __align__(16) float h_s[128];
    __shared__ float gates_s[512];
    int b = blockIdx.x, tid = threadIdx.x;
    int g = tid >> 7, j = tid & 127;

    float w[128];
    const float* wr = Whh + (size_t)(g * 128 + j) * 128;
    #pragma unroll
    for (int k = 0; k < 128; k += 4) {
        float4 v = *(const float4*)(wr + k);
        w[k] = v.x; w[k + 1] = v.y; w[k + 2] = v.z; w[k + 3] = v.w;
    }
    float h = h0[b * 128 + j];
    float c = c0[b * 128 + j];
    const float* gxb = gx + (size_t)b * 512;

    for (int t = 0; t < TT; t++) {
        float m = 1.0f - (float)done[t * 32 + b];
        c *= m;
        if (g == 0) h_s[j] = h * m;
        __syncthreads();
        float acc = 0.0f;
        #pragma unroll
        for (int k = 0; k < 128; k += 4) {
            float4 hv = *(const float4*)&h_s[k];
            acc = fmaf(w[k], hv.x, acc);
            acc = fmaf(w[k + 1], hv.y, acc);
            acc = fmaf(w[k + 2], hv.z, acc);
            acc = fmaf(w[k + 3], hv.w, acc);
        }
        acc += gxb[(size_t)t * 32 * 512 + (g << 7) + j];
        gates_s[(g << 7) + j] = acc;
        __syncthreads();
        float iv = sigmoid_f(gates_s[j]);
        float fv = sigmoid_f(gates_s[128 + j]);
        float gv = tanhf(gates_s[256 + j]);
        float ov = sigmoid_f(gates_s[384 + j]);
        c = fv * c + iv * gv;
        h = ov * tanhf(c);
        if (g == 0) hs[((size_t)t * 32 + b) * 128 + j] = f2bf(h);
    }
    if (g == 0) {
        out[12288 + b * 128 + j] = h;
        out[16384 + b * 128 + j] = c;
    }
}

// ---------------- heads: logits (2048x5), v (2048) ----------------
__global__ __launch_bounds__(256) void heads_kernel(
    const ushort_t* __restrict__ hs, const float* __restrict__ Wp,
    const float* __restrict__ bp, const float* __restrict__ Wv,
    const float* __restrict__ bv, float* __restrict__ out)
{
    int id = blockIdx.x * 256 + threadIdx.x;   // 12288 = 2048*6
    int n = id / 6, q = id % 6;
    const ushort_t* hrow = hs + (size_t)n * 128;
    if (q < 5) {
        float acc = bp[q];
        for (int k = 0; k < 128; k++) acc = fmaf(bf2f(hrow[k]), Wp[k * 5 + q], acc);
        out[n * 5 + q] = acc;
    } else {
        float acc = bv[0];
        for (int k = 0; k < 128; k++) acc = fmaf(bf2f(hrow[k]), Wv[k], acc);
        out[10240 + n] = acc;
    }
}

extern "C" void kernel_launch(void* const* d_in, const int* in_sizes, int n_in,
                              void* d_out, int out_size, void* d_ws, size_t ws_size,
                              hipStream_t stream) {
    const float* image = (const float*)d_in[0];
    const int*   pos   = (const int*)d_in[1];
    const int*   done  = (const int*)d_in[2];
    const float* h0    = (const float*)d_in[3];
    const float* c0    = (const float*)d_in[4];
    const float* W1    = (const float*)d_in[5];
    const float* b1    = (const float*)d_in[6];
    const float* W2    = (const float*)d_in[7];
    const float* b2    = (const float*)d_in[8];
    const float* W3    = (const float*)d_in[9];
    const float* b3    = (const float*)d_in[10];
    const float* Wfc   = (const float*)d_in[11];
    const float* bfc   = (const float*)d_in[12];
    const float* Wih   = (const float*)d_in[13];
    const float* Whh   = (const float*)d_in[14];
    const float* bih   = (const float*)d_in[15];
    const float* bhh   = (const float*)d_in[16];
    const float* Wp    = (const float*)d_in[17];
    const float* bp    = (const float*)d_in[18];
    const float* Wv    = (const float*)d_in[19];
    const float* bv    = (const float*)d_in[20];

    char* ws = (char*)d_ws;
    ushort_t* Wihb = (ushort_t*)(ws + 0);           //   524,288 B
    ushort_t* WfcT = (ushort_t*)(ws + 524288);      // 3,211,264 -> 3,735,552
    ushort_t* W1b  = (ushort_t*)(ws + 3735552);     //    16,384 -> 3,751,936
    ushort_t* W2b  = (ushort_t*)(ws + 3751936);     //    65,536 -> 3,817,472
    ushort_t* W3b  = (ushort_t*)(ws + 3817472);     //    73,728 -> 3,891,200
    ushort_t* out3 = (ushort_t*)(ws + 4194304);     // 12,845,056 -> 17,039,360
    ushort_t* feat = (ushort_t*)(ws + 17039360);    //  2,097,152 -> 19,136,512
    float*    gx   = (float*)(ws + 19136512);       //  4,194,304 -> 23,330,816
    ushort_t* hs   = (ushort_t*)(ws + 23330816);    //    524,288 -> 23,855,104

    float* out = (float*)d_out;

    prep_kernel<<<1024, 256, 0, stream>>>(Wih, Wihb);
    prep_convw_kernel<<<304, 256, 0, stream>>>(W1, W2, W3, W1b, W2b, W3b);
    wfct_kernel<<<392, 256, 0, stream>>>(Wfc, WfcT);
    convs_mfma<<<2048, 512, 0, stream>>>(image, W1b, b1, W2b, b2, W3b, b3, out3);
    fc_mfma_kernel<<<512, 256, 0, stream>>>(out3, WfcT, bfc, feat);
    gates_mfma_kernel<<<512, 256, 0, stream>>>(feat, Wihb, Wih, bih, bhh, pos, gx);
    lstm_kernel<<<32, 512, 0, stream>>>(gx, Whh, done, h0, c0, hs, out);
    heads_kernel<<<48, 256, 0, stream>>>(hs, Wp, bp, Wv, bv, out);
}

// Round 4
// 609.012 us; speedup vs baseline: 1.3047x; 1.3047x over previous
//
#include <hip/hip_runtime.h>

typedef unsigned short ushort_t;
typedef unsigned int uint_t;
typedef __attribute__((ext_vector_type(8))) short short8;
typedef __attribute__((ext_vector_type(4))) short short4v;
typedef __attribute__((ext_vector_type(4))) float floatx4;

__device__ __forceinline__ float bf2f(ushort_t u){
    union { uint_t i; float f; } c; c.i = ((uint_t)u) << 16; return c.f;
}
__device__ __forceinline__ ushort_t f2bf(float x){
    union { float f; uint_t i; } c; c.f = x;
    uint_t i = c.i;
    return (ushort_t)((i + 0x7fffu + ((i >> 16) & 1u)) >> 16);
}
// fast pack of 2 fp32 -> 2 bf16 (round-half-up): 2 adds + v_perm
__device__ __forceinline__ uint_t cvt2fast(float a, float b){
    union { float f; uint_t i; } ca, cb; ca.f = a; cb.f = b;
    uint_t ia = ca.i + 0x8000u, ib = cb.i + 0x8000u;
    return __builtin_amdgcn_perm(ib, ia, 0x07060302u);
}
__device__ __forceinline__ float relu_f(float x){ return fmaxf(x, 0.0f); }
__device__ __forceinline__ float sigmoid_f(float x){ return 1.0f / (1.0f + __expf(-x)); }

#define NT 2048
#define TT 64

// ---------------- prep: Wihb[j][k] = bf16(Wih[j][k]), k<512 ----------------
__global__ __launch_bounds__(256) void prep_kernel(
    const float* __restrict__ Wih, ushort_t* __restrict__ Wihb)
{
    int i = blockIdx.x * 256 + threadIdx.x;   // 262144
    int j = i >> 9, k = i & 511;
    Wihb[i] = f2bf(Wih[j * 532 + k]);
}

// ---------------- prep conv weights: W1b[8][32oc][32k], W2b[16][64oc][32ic], W3b[9][64oc][64ic] ----------------
__global__ __launch_bounds__(256) void prep_convw_kernel(
    const float* __restrict__ W1, const float* __restrict__ W2,
    const float* __restrict__ W3, ushort_t* __restrict__ W1b,
    ushort_t* __restrict__ W2b, ushort_t* __restrict__ W3b)
{
    int i = blockIdx.x * 256 + threadIdx.x;   // 77824 total
    if (i < 8192) {                           // W1b: k = kx*3+ic (24 real, pad 8 zeros)
        int ky = i >> 10, oc = (i >> 5) & 31, k = i & 31;
        float v = 0.0f;
        if (k < 24) { int kx = k / 3, ic = k % 3; v = W1[((ky * 8 + kx) * 3 + ic) * 32 + oc]; }
        W1b[i] = f2bf(v);
        return;
    }
    i -= 8192;
    if (i < 32768) {                          // W2b[kk][oc][ic]
        int kk = i >> 11, oc = (i >> 5) & 63, ic = i & 31;
        W2b[i] = f2bf(W2[(kk * 32 + ic) * 64 + oc]);
        return;
    }
    i -= 32768;
    if (i < 36864) {                          // W3b[p][oc][ic]
        int p = i >> 12, oc = (i >> 6) & 63, ic = i & 63;
        W3b[i] = f2bf(W3[(p * 64 + ic) * 64 + oc]);
    }
}

// ---------------- wfct: Wfc[3136][512] f32 -> WfcT[512][3136] bf16 ----------------
__global__ __launch_bounds__(256) void wfct_kernel(
    const float* __restrict__ Wfc, ushort_t* __restrict__ WfcT)
{
    __shared__ ushort_t t_s[64][65];
    int kb = blockIdx.x % 49, jb = blockIdx.x / 49;   // 49*8 blocks
    int k0 = kb * 64, j0 = jb * 64;
    int jj = threadIdx.x & 63, i4 = threadIdx.x >> 6;
    for (int rr = i4; rr < 64; rr += 4)
        t_s[rr][jj] = f2bf(Wfc[(size_t)(k0 + rr) * 512 + j0 + jj]);
    __syncthreads();
    for (int rr = i4; rr < 64; rr += 4)
        WfcT[(size_t)(j0 + rr) * 3136 + k0 + jj] = t_s[jj][rr];
}

// ---------------- fused convs via MFMA, block per sample ----------------
// 256 threads (4 waves), round-0 work split (known-good register regime:
// ~60 arch VGPR + AGPR weight frags; (512,8) spilled catastrophically in R2).
// New: K-chunk-planar LDS layouts, conflict-free fragment reads:
//   c1: [parity][q=ch/8][200 pos][8ch]  (25,600 B, exactly the data)
//   c2: [kc=ch/8][81 pos][8ch]          (10,368 B) ALIASED over c1 region --
//       conv2 accumulates all outputs in regs, extra barrier, then stores.
// LDS = 25,600 B -> 6 blocks/CU (was 4); launch_bounds(256,6) caps VGPR ~341.
__global__ __launch_bounds__(256, 6) void convs_mfma(
    const float* __restrict__ img,
    const ushort_t* __restrict__ W1b, const float* __restrict__ b1,
    const ushort_t* __restrict__ W2b, const float* __restrict__ b2,
    const ushort_t* __restrict__ W3b, const float* __restrict__ b3,
    ushort_t* __restrict__ out3)
{
    // halves; c1 plane p at p*6400 + q*1600 + pos*8 + c
    // c2 (after re-use) at kc*648 + pos*8 + c
    __shared__ __align__(16) ushort_t smem[12800];   // 25,600 B

    int n = blockIdx.x, tid = threadIdx.x;
    int w = tid >> 6, lane = tid & 63;
    int r = lane & 15, q = lane >> 4;

    // ---- conv1: 20x20x32, k=8 s=4; K=32 (kx*3+ic, B-rows zero-padded 24..31) ----
    // wave = px-phase; each wave computes BOTH 16-oc tiles from one A-fragment
    {
        short8 bf0[8], bf1[8];
        #pragma unroll
        for (int ky = 0; ky < 8; ky++) {
            bf0[ky] = *(const short8*)(W1b + (ky * 32 +      r) * 32 + q * 8);
            bf1[ky] = *(const short8*)(W1b + (ky * 32 + 16 + r) * 32 + q * 8);
        }
        float bb0 = b1[r], bb1 = b1[16 + r];
        const float* abase = img + (size_t)n * 21168;
        for (int t = w; t < 25; t += 4) {
            int pxa = t * 16 + r;
            int oy = pxa / 20, ox = pxa % 20;
            floatx4 acc0 = {0.f, 0.f, 0.f, 0.f}, acc1 = {0.f, 0.f, 0.f, 0.f};
            #pragma unroll
            for (int ky = 0; ky < 8; ky++) {
                short8 a = {0,0,0,0,0,0,0,0};
                if (q < 3) {
                    const float* p = abase + ((oy * 4 + ky) * 84 + ox * 4) * 3 + q * 8;
                    float4 f0 = *(const float4*)p;
                    float4 f1 = *(const float4*)(p + 4);
                    union { uint_t u[4]; short8 s; } pk;
                    pk.u[0] = cvt2fast(f0.x, f0.y);
                    pk.u[1] = cvt2fast(f0.z, f0.w);
                    pk.u[2] = cvt2fast(f1.x, f1.y);
                    pk.u[3] = cvt2fast(f1.z, f1.w);
                    a = pk.s;
                }
                acc0 = __builtin_amdgcn_mfma_f32_16x16x32_bf16(a, bf0[ky], acc0, 0, 0, 0);
                acc1 = __builtin_amdgcn_mfma_f32_16x16x32_bf16(a, bf1[ky], acc1, 0, 0, 0);
            }
            int pxs = t * 16 + q * 4;
            #pragma unroll
            for (int i = 0; i < 4; i++) {
                int px = pxs + i;
                int y = px / 20, x = px % 20;
                // parity plane = x&1 (== i&1 since pxs even), pos = y*10 + x/2
                int base = (x & 1) * 6400 + (y * 10 + (x >> 1)) * 8 + (r & 7);
                smem[base + ((r >> 3)    ) * 1600] = f2bf(relu_f(acc0[i] + bb0));
                smem[base + (2 + (r >> 3)) * 1600] = f2bf(relu_f(acc1[i] + bb1));
            }
        }
    }
    __syncthreads();

    // ---- conv2: 9x9x64, k=4 s=2; 16 pos x K=32; wave = oc-tile ----
    // Phase A: accumulate all 6 t-tiles into registers (c1 still live).
    float accv[6][4];
    {
        int oct = w;
        short8 bfr[16];
        #pragma unroll
        for (int kk = 0; kk < 16; kk++)
            bfr[kk] = *(const short8*)(W2b + (kk * 64 + oct * 16 + r) * 32 + q * 8);
        #pragma unroll
        for (int t = 0; t < 6; t++) {
            int pxa = min(t * 16 + r, 80);
            int oy = pxa / 9, ox = pxa % 9;
            floatx4 acc = {0.f, 0.f, 0.f, 0.f};
            #pragma unroll
            for (int ky = 0; ky < 4; ky++) {
                #pragma unroll
                for (int kxh = 0; kxh < 2; kxh++) {   // kx = 2*kxh (even plane), 2*kxh+1 (odd)
                    int pos = (oy * 2 + ky) * 10 + ox + kxh;
                    const ushort_t* pe = smem + q * 1600 + pos * 8;
                    short8 ae = *(const short8*)pe;
                    short8 ao = *(const short8*)(pe + 6400);
                    acc = __builtin_amdgcn_mfma_f32_16x16x32_bf16(ae, bfr[ky * 4 + kxh * 2],     acc, 0, 0, 0);
                    acc = __builtin_amdgcn_mfma_f32_16x16x32_bf16(ao, bfr[ky * 4 + kxh * 2 + 1], acc, 0, 0, 0);
                }
            }
            #pragma unroll
            for (int i = 0; i < 4; i++) accv[t][i] = acc[i];
        }
    }
    __syncthreads();
    // Phase B: store c2 into the re-used LDS region.
    {
        int oct = w;
        float bb = b2[oct * 16 + r];
        int kcb = (2 * oct + (r >> 3)) * 648 + (r & 7);
        #pragma unroll
        for (int t = 0; t < 6; t++) {
            #pragma unroll
            for (int i = 0; i < 4; i++) {
                int px = t * 16 + q * 4 + i;
                if (px < 81)
                    smem[kcb + px * 8] = f2bf(relu_f(accv[t][i] + bb));
            }
        }
    }
    __syncthreads();

    // ---- conv3: 7x7x64, k=3 s=1; 9 pos x K=64 (2 chunks); wave = oc-tile ----
    {
        int oct = w;
        short8 bfr[18];
        #pragma unroll
        for (int p = 0; p < 9; p++) {
            #pragma unroll
            for (int h = 0; h < 2; h++)
                bfr[p * 2 + h] = *(const short8*)(W3b + (p * 64 + oct * 16 + r) * 64 + h * 32 + q * 8);
        }
        float bb = b3[oct * 16 + r];
        for (int t = 0; t < 4; t++) {
            int pxa = min(t * 16 + r, 48);
            int oy = pxa / 7, ox = pxa % 7;
            floatx4 acc = {0.f, 0.f, 0.f, 0.f};
            #pragma unroll
            for (int ky = 0; ky < 3; ky++) {
                #pragma unroll
                for (int kx = 0; kx < 3; kx++) {
                    int qin = (oy + ky) * 9 + ox + kx;
                    const ushort_t* p0 = smem + q * 648 + qin * 8;
                    short8 a0 = *(const short8*)p0;
                    short8 a1 = *(const short8*)(p0 + 4 * 648);
                    acc = __builtin_amdgcn_mfma_f32_16x16x32_bf16(a0, bfr[(ky * 3 + kx) * 2],     acc, 0, 0, 0);
                    acc = __builtin_amdgcn_mfma_f32_16x16x32_bf16(a1, bfr[(ky * 3 + kx) * 2 + 1], acc, 0, 0, 0);
                }
            }
            #pragma unroll
            for (int i = 0; i < 4; i++) {
                int px = t * 16 + q * 4 + i;
                if (px < 49)
                    out3[(size_t)n * 3136 + px * 64 + oct * 16 + r] = f2bf(relu_f(acc[i] + bb));
            }
        }
    }
}

// ---------------- FC via MFMA: feat[2048][512] = relu(out3 @ Wfc + bfc) ----------------
__global__ __launch_bounds__(256) void fc_mfma_kernel(
    const ushort_t* __restrict__ A, const ushort_t* __restrict__ BT,
    const float* __restrict__ bfc, ushort_t* __restrict__ feat)
{
    int mb = blockIdx.x & 63, nb = blockIdx.x >> 6;   // 64 x 8
    int tid = threadIdx.x;
    int w = tid >> 6, lane = tid & 63;
    int r = lane & 15, q = lane >> 4;
    int m0 = mb * 32 + (w & 1) * 16;
    int n0 = nb * 64 + (w >> 1) * 32;
    const ushort_t* arow  = A  + (size_t)(m0 + r) * 3136 + q * 8;
    const ushort_t* brow0 = BT + (size_t)(n0 + r) * 3136 + q * 8;
    const ushort_t* brow1 = BT + (size_t)(n0 + 16 + r) * 3136 + q * 8;
    floatx4 acc0 = {0.f, 0.f, 0.f, 0.f}, acc1 = {0.f, 0.f, 0.f, 0.f};
    short8 a  = *(const short8*)arow;
    short8 b0 = *(const short8*)brow0;
    short8 b1 = *(const short8*)brow1;
    for (int kk = 1; kk < 98; kk++) {
        short8 an  = *(const short8*)(arow  + kk * 32);
        short8 b0n = *(const short8*)(brow0 + kk * 32);
        short8 b1n = *(const short8*)(brow1 + kk * 32);
        acc0 = __builtin_amdgcn_mfma_f32_16x16x32_bf16(a, b0, acc0, 0, 0, 0);
        acc1 = __builtin_amdgcn_mfma_f32_16x16x32_bf16(a, b1, acc1, 0, 0, 0);
        a = an; b0 = b0n; b1 = b1n;
    }
    acc0 = __builtin_amdgcn_mfma_f32_16x16x32_bf16(a, b0, acc0, 0, 0, 0);
    acc1 = __builtin_amdgcn_mfma_f32_16x16x32_bf16(a, b1, acc1, 0, 0, 0);
    int c0 = n0 + r, c1 = n0 + 16 + r;
    float bb0 = bfc[c0], bb1 = bfc[c1];
    #pragma unroll
    for (int i = 0; i < 4; i++) {
        int row = m0 + q * 4 + i;
        feat[(size_t)row * 512 + c0] = f2bf(relu_f(acc0[i] + bb0));
        feat[(size_t)row * 512 + c1] = f2bf(relu_f(acc1[i] + bb1));
    }
}

// ---------------- gates via MFMA: gx[2048][512] = feat @ Wih[:,:512]^T + onehot + bias ----------------
__global__ __launch_bounds__(256) void gates_mfma_kernel(
    const ushort_t* __restrict__ A, const ushort_t* __restrict__ Wihb,
    const float* __restrict__ Wih, const float* __restrict__ bih,
    const float* __restrict__ bhh, const int* __restrict__ pos,
    float* __restrict__ gx)
{
    int mb = blockIdx.x & 63, nb = blockIdx.x >> 6;   // 64 x 8
    int tid = threadIdx.x;
    int w = tid >> 6, lane = tid & 63;
    int r = lane & 15, q = lane >> 4;
    int m0 = mb * 32 + (w & 1) * 16;
    int n0 = nb * 64 + (w >> 1) * 32;
    const ushort_t* arow  = A    + (size_t)(m0 + r) * 512 + q * 8;
    const ushort_t* brow0 = Wihb + (size_t)(n0 + r) * 512 + q * 8;
    const ushort_t* brow1 = Wihb + (size_t)(n0 + 16 + r) * 512 + q * 8;
    floatx4 acc0 = {0.f, 0.f, 0.f, 0.f}, acc1 = {0.f, 0.f, 0.f, 0.f};
    short8 a  = *(const short8*)arow;
    short8 b0 = *(const short8*)brow0;
    short8 b1 = *(const short8*)brow1;
    for (int kk = 1; kk < 16; kk++) {
        short8 an  = *(const short8*)(arow  + kk * 32);
        short8 b0n = *(const short8*)(brow0 + kk * 32);
        short8 b1n = *(const short8*)(brow1 + kk * 32);
        acc0 = __builtin_amdgcn_mfma_f32_16x16x32_bf16(a, b0, acc0, 0, 0, 0);
        acc1 = __builtin_amdgcn_mfma_f32_16x16x32_bf16(a, b1, acc1, 0, 0, 0);
        a = an; b0 = b0n; b1 = b1n;
    }
    acc0 = __builtin_amdgcn_mfma_f32_16x16x32_bf16(a, b0, acc0, 0, 0, 0);
    acc1 = __builtin_amdgcn_mfma_f32_16x16x32_bf16(a, b1, acc1, 0, 0, 0);
    int j0 = n0 + r, j1 = n0 + 16 + r;
    float bias0 = bih[j0] + bhh[j0];
    float bias1 = bih[j1] + bhh[j1];
    #pragma unroll
    for (int i = 0; i < 4; i++) {
        int row = m0 + q * 4 + i;
        int p0 = pos[2 * row], p1 = pos[2 * row + 1];
        float oh0 = Wih[(size_t)j0 * 532 + 512 + p0] + Wih[(size_t)j0 * 532 + 522 + p1];
        float oh1 = Wih[(size_t)j1 * 532 + 512 + p0] + Wih[(size_t)j1 * 532 + 522 + p1];
        gx[(size_t)row * 512 + j0] = acc0[i] + bias0 + oh0;
        gx[(size_t)row * 512 + j1] = acc1[i] + bias1 + oh1;
    }
}

// ---------------- LSTM: 32 independent blocks (one per batch element) ----------------
__global__ __launch_bounds__(512, 2) void lstm_kernel(
    const float* __restrict__ gx, const float* __restrict__ Whh,
    const int* __restrict__ done, const float* __restrict__ h0,
    const float* __restrict__ c0, ushort_t* __restrict__ hs,
    float* __restrict__ out)
{
    __shared__ __align__(16) float h_s[128];
    __shared__ float gates_s[512];
    int b = blockIdx.x, tid = threadIdx.x;
    int g = tid >> 7, j = tid & 127;

    float w[128];
    const float* wr = Whh + (size_t)(g * 128 + j) * 128;
    #pragma unroll
    for (int k = 0; k < 128; k += 4) {
        float4 v = *(const float4*)(wr + k);
        w[k] = v.x; w[k + 1] = v.y; w[k + 2] = v.z; w[k + 3] = v.w;
    }
    float h = h0[b * 128 + j];
    float c = c0[b * 128 + j];
    const float* gxb = gx + (size_t)b * 512;

    for (int t = 0; t < TT; t++) {
        float m = 1.0f - (float)done[t * 32 + b];
        c *= m;
        if (g == 0) h_s[j] = h * m;
        __syncthreads();
        float acc = 0.0f;
        #pragma unroll
        for (int k = 0; k < 128; k += 4) {
            float4 hv = *(const float4*)&h_s[k];
            acc = fmaf(w[k], hv.x, acc);
            acc = fmaf(w[k + 1], hv.y, acc);
            acc = fmaf(w[k + 2], hv.z, acc);
            acc = fmaf(w[k + 3], hv.w, acc);
        }
        acc += gxb[(size_t)t * 32 * 512 + (g << 7) + j];
        gates_s[(g << 7) + j] = acc;
        __syncthreads();
        float iv = sigmoid_f(gates_s[j]);
        float fv = sigmoid_f(gates_s[128 + j]);
        float gv = tanhf(gates_s[256 + j]);
        float ov = sigmoid_f(gates_s[384 + j]);
        c = fv * c + iv * gv;
        h = ov * tanhf(c);
        if (g == 0) hs[((size_t)t * 32 + b) * 128 + j] = f2bf(h);
    }
    if (g == 0) {
        out[12288 + b * 128 + j] = h;
        out[16384 + b * 128 + j] = c;
    }
}

// ---------------- heads: logits (2048x5), v (2048) ----------------
__global__ __launch_bounds__(256) void heads_kernel(
    const ushort_t* __restrict__ hs, const float* __restrict__ Wp,
    const float* __restrict__ bp, const float* __restrict__ Wv,
    const float* __restrict__ bv, float* __restrict__ out)
{
    int id = blockIdx.x * 256 + threadIdx.x;   // 12288 = 2048*6
    int n = id / 6, q = id % 6;
    const ushort_t* hrow = hs + (size_t)n * 128;
    if (q < 5) {
        float acc = bp[q];
        for (int k = 0; k < 128; k++) acc = fmaf(bf2f(hrow[k]), Wp[k * 5 + q], acc);
        out[n * 5 + q] = acc;
    } else {
        float acc = bv[0];
        for (int k = 0; k < 128; k++) acc = fmaf(bf2f(hrow[k]), Wv[k], acc);
        out[10240 + n] = acc;
    }
}

extern "C" void kernel_launch(void* const* d_in, const int* in_sizes, int n_in,
                              void* d_out, int out_size, void* d_ws, size_t ws_size,
                              hipStream_t stream) {
    const float* image = (const float*)d_in[0];
    const int*   pos   = (const int*)d_in[1];
    const int*   done  = (const int*)d_in[2];
    const float* h0    = (const float*)d_in[3];
    const float* c0    = (const float*)d_in[4];
    const float* W1    = (const float*)d_in[5];
    const float* b1    = (const float*)d_in[6];
    const float* W2    = (const float*)d_in[7];
    const float* b2    = (const float*)d_in[8];
    const float* W3    = (const float*)d_in[9];
    const float* b3    = (const float*)d_in[10];
    const float* Wfc   = (const float*)d_in[11];
    const float* bfc   = (const float*)d_in[12];
    const float* Wih   = (const float*)d_in[13];
    const float* Whh   = (const float*)d_in[14];
    const float* bih   = (const float*)d_in[15];
    const float* bhh   = (const float*)d_in[16];
    const float* Wp    = (const float*)d_in[17];
    const float* bp    = (const float*)d_in[18];
    const float* Wv    = (const float*)d_in[19];
    const float* bv    = (const float*)d_in[20];

    char* ws = (char*)d_ws;
    ushort_t* Wihb = (ushort_t*)(ws + 0);           //   524,288 B
    ushort_t* WfcT = (ushort_t*)(ws + 524288);      // 3,211,264 -> 3,735,552
    ushort_t* W1b  = (ushort_t*)(ws + 3735552);     //    16,384 -> 3,751,936
    ushort_t* W2b  = (ushort_t*)(ws + 3751936);     //    65,536 -> 3,817,472
    ushort_t* W3b  = (ushort_t*)(ws + 3817472);     //    73,728 -> 3,891,200
    ushort_t* out3 = (ushort_t*)(ws + 4194304);     // 12,845,056 -> 17,039,360
    ushort_t* feat = (ushort_t*)(ws + 17039360);    //  2,097,152 -> 19,136,512
    float*    gx   = (float*)(ws + 19136512);       //  4,194,304 -> 23,330,816
    ushort_t* hs   = (ushort_t*)(ws + 23330816);    //    524,288 -> 23,855,104

    float* out = (float*)d_out;

    prep_kernel<<<1024, 256, 0, stream>>>(Wih, Wihb);
    prep_convw_kernel<<<304, 256, 0, stream>>>(W1, W2, W3, W1b, W2b, W3b);
    wfct_kernel<<<392, 256, 0, stream>>>(Wfc, WfcT);
    convs_mfma<<<2048, 256, 0, stream>>>(image, W1b, b1, W2b, b2, W3b, b3, out3);
    fc_mfma_kernel<<<512, 256, 0, stream>>>(out3, WfcT, bfc, feat);
    gates_mfma_kernel<<<512, 256, 0, stream>>>(feat, Wihb, Wih, bih, bhh, pos, gx);
    lstm_kernel<<<32, 512, 0, stream>>>(gx, Whh, done, h0, c0, hs, out);
    heads_kernel<<<48, 256, 0, stream>>>(hs, Wp, bp, Wv, bv, out);
}

// Round 5
// 584.778 us; speedup vs baseline: 1.3588x; 1.0414x over previous
//
#include <hip/hip_runtime.h>

typedef unsigned short ushort_t;
typedef unsigned int uint_t;
typedef __attribute__((ext_vector_type(8))) short short8;
typedef __attribute__((ext_vector_type(4))) short short4v;
typedef __attribute__((ext_vector_type(4))) float floatx4;

__device__ __forceinline__ float bf2f(ushort_t u){
    union { uint_t i; float f; } c; c.i = ((uint_t)u) << 16; return c.f;
}
__device__ __forceinline__ ushort_t f2bf(float x){
    union { float f; uint_t i; } c; c.f = x;
    uint_t i = c.i;
    return (ushort_t)((i + 0x7fffu + ((i >> 16) & 1u)) >> 16);
}
// fast pack of 2 fp32 -> 2 bf16 (round-half-up): 2 adds + v_perm
__device__ __forceinline__ uint_t cvt2fast(float a, float b){
    union { float f; uint_t i; } ca, cb; ca.f = a; cb.f = b;
    uint_t ia = ca.i + 0x8000u, ib = cb.i + 0x8000u;
    return __builtin_amdgcn_perm(ib, ia, 0x07060302u);
}
__device__ __forceinline__ float relu_f(float x){ return fmaxf(x, 0.0f); }
__device__ __forceinline__ float sigmoid_f(float x){ return 1.0f / (1.0f + __expf(-x)); }

#define NT 2048
#define TT 64

// ---------------- prep: Wihb[j][k] = bf16(Wih[j][k]), k<512 ----------------
__global__ __launch_bounds__(256) void prep_kernel(
    const float* __restrict__ Wih, ushort_t* __restrict__ Wihb)
{
    int i = blockIdx.x * 256 + threadIdx.x;   // 262144
    int j = i >> 9, k = i & 511;
    Wihb[i] = f2bf(Wih[j * 532 + k]);
}

// ---------------- prep conv weights: W1b[8][32oc][32k], W2b[16][64oc][32ic], W3b[9][64oc][64ic] ----------------
__global__ __launch_bounds__(256) void prep_convw_kernel(
    const float* __restrict__ W1, const float* __restrict__ W2,
    const float* __restrict__ W3, ushort_t* __restrict__ W1b,
    ushort_t* __restrict__ W2b, ushort_t* __restrict__ W3b)
{
    int i = blockIdx.x * 256 + threadIdx.x;   // 77824 total
    if (i < 8192) {                           // W1b: k = kx*3+ic (24 real, pad 8 zeros)
        int ky = i >> 10, oc = (i >> 5) & 31, k = i & 31;
        float v = 0.0f;
        if (k < 24) { int kx = k / 3, ic = k % 3; v = W1[((ky * 8 + kx) * 3 + ic) * 32 + oc]; }
        W1b[i] = f2bf(v);
        return;
    }
    i -= 8192;
    if (i < 32768) {                          // W2b[kk][oc][ic]
        int kk = i >> 11, oc = (i >> 5) & 63, ic = i & 31;
        W2b[i] = f2bf(W2[(kk * 32 + ic) * 64 + oc]);
        return;
    }
    i -= 32768;
    if (i < 36864) {                          // W3b[p][oc][ic]
        int p = i >> 12, oc = (i >> 6) & 63, ic = i & 63;
        W3b[i] = f2bf(W3[(p * 64 + ic) * 64 + oc]);
    }
}

// ---------------- wfct: Wfc[3136][512] f32 -> WfcT[512][3136] bf16 ----------------
__global__ __launch_bounds__(256) void wfct_kernel(
    const float* __restrict__ Wfc, ushort_t* __restrict__ WfcT)
{
    __shared__ ushort_t t_s[64][65];
    int kb = blockIdx.x % 49, jb = blockIdx.x / 49;   // 49*8 blocks
    int k0 = kb * 64, j0 = jb * 64;
    int jj = threadIdx.x & 63, i4 = threadIdx.x >> 6;
    for (int rr = i4; rr < 64; rr += 4)
        t_s[rr][jj] = f2bf(Wfc[(size_t)(k0 + rr) * 512 + j0 + jj]);
    __syncthreads();
    for (int rr = i4; rr < 64; rr += 4)
        WfcT[(size_t)(j0 + rr) * 3136 + k0 + jj] = t_s[jj][rr];
}

// ---------------- fused convs via MFMA, block per sample ----------------
// 256 threads (4 waves). Registers are the occupancy binder (R2/R4 spills at
// caps 64/85; R0 demand <=128). This version cuts per-phase register demand to
// ~<=80 (conv1 one-oct waves; conv2 kk-chunked 2x8 frags; conv3 ky-passes) and
// declares launch_bounds(256,5): cap 102, 20 waves/CU (62.5%).
// LDS: K-chunk-planar, chunk strides padded for bank spread:
//   c1: chunk = parity*4 + (ch>>3), addr = chunk*1608 + pos*8 + (ch&7)
//   c2 (aliased over c1 after extra barrier): kc*656 + px*8 + (ch&7)
// Chunk strides 1608/656 halves rotate banks by 4/8 per chunk; frag reads stay
// 16B-aligned (3216 B / 1312 B strides).
__global__ __launch_bounds__(256, 5) void convs_mfma(
    const float* __restrict__ img,
    const ushort_t* __restrict__ W1b, const float* __restrict__ b1,
    const ushort_t* __restrict__ W2b, const float* __restrict__ b2,
    const ushort_t* __restrict__ W3b, const float* __restrict__ b3,
    ushort_t* __restrict__ out3)
{
    __shared__ __align__(16) ushort_t smem[12864];   // 25,728 B

    int n = blockIdx.x, tid = threadIdx.x;
    int w = tid >> 6, lane = tid & 63;
    int r = lane & 15, q = lane >> 4;

    // ---- conv1: 20x20x32, k=8 s=4; K=32 (kx*3+ic, rows 24..31 zero) ----
    // wave = (oct = w&1, phase = w>>1): 8 weight frags per wave (32 regs)
    {
        int oct = w & 1, ph = w >> 1;
        short8 bw[8];
        #pragma unroll
        for (int ky = 0; ky < 8; ky++)
            bw[ky] = *(const short8*)(W1b + (ky * 32 + oct * 16 + r) * 32 + q * 8);
        float bb = b1[oct * 16 + r];
        const float* abase = img + (size_t)n * 21168;
        for (int t = ph; t < 25; t += 2) {
            int pxa = t * 16 + r;
            int oy = pxa / 20, ox = pxa % 20;
            floatx4 acc = {0.f, 0.f, 0.f, 0.f};
            #pragma unroll
            for (int ky = 0; ky < 8; ky++) {
                short8 a = {0,0,0,0,0,0,0,0};
                if (q < 3) {
                    const float* p = abase + ((oy * 4 + ky) * 84 + ox * 4) * 3 + q * 8;
                    float4 f0 = *(const float4*)p;
                    float4 f1 = *(const float4*)(p + 4);
                    union { uint_t u[4]; short8 s; } pk;
                    pk.u[0] = cvt2fast(f0.x, f0.y);
                    pk.u[1] = cvt2fast(f0.z, f0.w);
                    pk.u[2] = cvt2fast(f1.x, f1.y);
                    pk.u[3] = cvt2fast(f1.z, f1.w);
                    a = pk.s;
                }
                acc = __builtin_amdgcn_mfma_f32_16x16x32_bf16(a, bw[ky], acc, 0, 0, 0);
            }
            int pxs = t * 16 + q * 4;
            #pragma unroll
            for (int i = 0; i < 4; i++) {
                int px = pxs + i;
                int y = px / 20, x = px % 20;
                int chunk = (x & 1) * 4 + oct * 2 + (r >> 3);
                smem[chunk * 1608 + (y * 10 + (x >> 1)) * 8 + (r & 7)] = f2bf(relu_f(acc[i] + bb));
            }
        }
    }
    __syncthreads();

    // ---- conv2: 9x9x64, k=4 s=2; wave = oc-tile; kk-chunked weights (2x8) ----
    float accv[6][4];
    #pragma unroll
    for (int t = 0; t < 6; t++) {
        #pragma unroll
        for (int i = 0; i < 4; i++) accv[t][i] = 0.0f;
    }
    {
        int oct = w;
        #pragma unroll
        for (int half = 0; half < 2; half++) {   // ky pair {0,1} then {2,3}
            short8 bfr[8];
            #pragma unroll
            for (int kk2 = 0; kk2 < 8; kk2++)
                bfr[kk2] = *(const short8*)(W2b + ((half * 8 + kk2) * 64 + oct * 16 + r) * 32 + q * 8);
            #pragma unroll
            for (int t = 0; t < 6; t++) {
                int pxa = min(t * 16 + r, 80);
                int oy = pxa / 9, ox = pxa % 9;
                floatx4 acc = {accv[t][0], accv[t][1], accv[t][2], accv[t][3]};
                #pragma unroll
                for (int ky2 = 0; ky2 < 2; ky2++) {
                    int ky = half * 2 + ky2;
                    #pragma unroll
                    for (int kxh = 0; kxh < 2; kxh++) {   // kx = 2*kxh / 2*kxh+1
                        int pos = (oy * 2 + ky) * 10 + ox + kxh;
                        const ushort_t* pe = smem + q * 1608 + pos * 8;
                        short8 ae = *(const short8*)pe;
                        short8 ao = *(const short8*)(pe + 4 * 1608);
                        acc = __builtin_amdgcn_mfma_f32_16x16x32_bf16(ae, bfr[ky2 * 4 + kxh * 2],     acc, 0, 0, 0);
                        acc = __builtin_amdgcn_mfma_f32_16x16x32_bf16(ao, bfr[ky2 * 4 + kxh * 2 + 1], acc, 0, 0, 0);
                    }
                }
                #pragma unroll
                for (int i = 0; i < 4; i++) accv[t][i] = acc[i];
            }
        }
    }
    __syncthreads();
    // store c2 into re-used LDS region
    {
        int oct = w;
        float bb = b2[oct * 16 + r];
        int kcb = (oct * 2 + (r >> 3)) * 656 + (r & 7);
        #pragma unroll
        for (int t = 0; t < 6; t++) {
            #pragma unroll
            for (int i = 0; i < 4; i++) {
                int px = t * 16 + q * 4 + i;
                if (px < 81)
                    smem[kcb + px * 8] = f2bf(relu_f(accv[t][i] + bb));
            }
        }
    }
    __syncthreads();

    // ---- conv3: 7x7x64, k=3 s=1; wave = oc-tile; ky-pass weights (3x6 frags) ----
    {
        int oct = w;
        float acct[4][4];
        #pragma unroll
        for (int t = 0; t < 4; t++) {
            #pragma unroll
            for (int i = 0; i < 4; i++) acct[t][i] = 0.0f;
        }
        #pragma unroll
        for (int ky = 0; ky < 3; ky++) {
            short8 bfr[6];
            #pragma unroll
            for (int kx = 0; kx < 3; kx++) {
                #pragma unroll
                for (int h = 0; h < 2; h++)
                    bfr[kx * 2 + h] = *(const short8*)(W3b + ((ky * 3 + kx) * 64 + oct * 16 + r) * 64 + h * 32 + q * 8);
            }
            #pragma unroll
            for (int t = 0; t < 4; t++) {
                int pxa = min(t * 16 + r, 48);
                int oy = pxa / 7, ox = pxa % 7;
                floatx4 acc = {acct[t][0], acct[t][1], acct[t][2], acct[t][3]};
                #pragma unroll
                for (int kx = 0; kx < 3; kx++) {
                    int qin = (oy + ky) * 9 + ox + kx;
                    const ushort_t* p0 = smem + q * 656 + qin * 8;
                    short8 a0 = *(const short8*)p0;
                    short8 a1 = *(const short8*)(p0 + 4 * 656);
                    acc = __builtin_amdgcn_mfma_f32_16x16x32_bf16(a0, bfr[kx * 2],     acc, 0, 0, 0);
                    acc = __builtin_amdgcn_mfma_f32_16x16x32_bf16(a1, bfr[kx * 2 + 1], acc, 0, 0, 0);
                }
                #pragma unroll
                for (int i = 0; i < 4; i++) acct[t][i] = acc[i];
            }
        }
        float bb = b3[oct * 16 + r];
        #pragma unroll
        for (int t = 0; t < 4; t++) {
            #pragma unroll
            for (int i = 0; i < 4; i++) {
                int px = t * 16 + q * 4 + i;
                if (px < 49)
                    out3[(size_t)n * 3136 + px * 64 + oct * 16 + r] = f2bf(relu_f(acct[t][i] + bb));
            }
        }
    }
}

// ---------------- FC via MFMA: feat[2048][512] = relu(out3 @ Wfc + bfc) ----------------
__global__ __launch_bounds__(256) void fc_mfma_kernel(
    const ushort_t* __restrict__ A, const ushort_t* __restrict__ BT,
    const float* __restrict__ bfc, ushort_t* __restrict__ feat)
{
    int mb = blockIdx.x & 63, nb = blockIdx.x >> 6;   // 64 x 8
    int tid = threadIdx.x;
    int w = tid >> 6, lane = tid & 63;
    int r = lane & 15, q = lane >> 4;
    int m0 = mb * 32 + (w & 1) * 16;
    int n0 = nb * 64 + (w >> 1) * 32;
    const ushort_t* arow  = A  + (size_t)(m0 + r) * 3136 + q * 8;
    const ushort_t* brow0 = BT + (size_t)(n0 + r) * 3136 + q * 8;
    const ushort_t* brow1 = BT + (size_t)(n0 + 16 + r) * 3136 + q * 8;
    floatx4 acc0 = {0.f, 0.f, 0.f, 0.f}, acc1 = {0.f, 0.f, 0.f, 0.f};
    short8 a  = *(const short8*)arow;
    short8 b0 = *(const short8*)brow0;
    short8 b1 = *(const short8*)brow1;
    for (int kk = 1; kk < 98; kk++) {
        short8 an  = *(const short8*)(arow  + kk * 32);
        short8 b0n = *(const short8*)(brow0 + kk * 32);
        short8 b1n = *(const short8*)(brow1 + kk * 32);
        acc0 = __builtin_amdgcn_mfma_f32_16x16x32_bf16(a, b0, acc0, 0, 0, 0);
        acc1 = __builtin_amdgcn_mfma_f32_16x16x32_bf16(a, b1, acc1, 0, 0, 0);
        a = an; b0 = b0n; b1 = b1n;
    }
    acc0 = __builtin_amdgcn_mfma_f32_16x16x32_bf16(a, b0, acc0, 0, 0, 0);
    acc1 = __builtin_amdgcn_mfma_f32_16x16x32_bf16(a, b1, acc1, 0, 0, 0);
    int c0 = n0 + r, c1 = n0 + 16 + r;
    float bb0 = bfc[c0], bb1 = bfc[c1];
    #pragma unroll
    for (int i = 0; i < 4; i++) {
        int row = m0 + q * 4 + i;
        feat[(size_t)row * 512 + c0] = f2bf(relu_f(acc0[i] + bb0));
        feat[(size_t)row * 512 + c1] = f2bf(relu_f(acc1[i] + bb1));
    }
}

// ---------------- gates via MFMA: gx[2048][512] = feat @ Wih[:,:512]^T + onehot + bias ----------------
__global__ __launch_bounds__(256) void gates_mfma_kernel(
    const ushort_t* __restrict__ A, const ushort_t* __restrict__ Wihb,
    const float* __restrict__ Wih, const float* __restrict__ bih,
    const float* __restrict__ bhh, const int* __restrict__ pos,
    float* __restrict__ gx)
{
    int mb = blockIdx.x & 63, nb = blockIdx.x >> 6;   // 64 x 8
    int tid = threadIdx.x;
    int w = tid >> 6, lane = tid & 63;
    int r = lane & 15, q = lane >> 4;
    int m0 = mb * 32 + (w & 1) * 16;
    int n0 = nb * 64 + (w >> 1) * 32;
    const ushort_t* arow  = A    + (size_t)(m0 + r) * 512 + q * 8;
    const ushort_t* brow0 = Wihb + (size_t)(n0 + r) * 512 + q * 8;
    const ushort_t* brow1 = Wihb + (size_t)(n0 + 16 + r) * 512 + q * 8;
    floatx4 acc0 = {0.f, 0.f, 0.f, 0.f}, acc1 = {0.f, 0.f, 0.f, 0.f};
    short8 a  = *(const short8*)arow;
    short8 b0 = *(const short8*)brow0;
    short8 b1 = *(const short8*)brow1;
    for (int kk = 1; kk < 16; kk++) {
        short8 an  = *(const short8*)(arow  + kk * 32);
        short8 b0n = *(const short8*)(brow0 + kk * 32);
        short8 b1n = *(const short8*)(brow1 + kk * 32);
        acc0 = __builtin_amdgcn_mfma_f32_16x16x32_bf16(a, b0, acc0, 0, 0, 0);
        acc1 = __builtin_amdgcn_mfma_f32_16x16x32_bf16(a, b1, acc1, 0, 0, 0);
        a = an; b0 = b0n; b1 = b1n;
    }
    acc0 = __builtin_amdgcn_mfma_f32_16x16x32_bf16(a, b0, acc0, 0, 0, 0);
    acc1 = __builtin_amdgcn_mfma_f32_16x16x32_bf16(a, b1, acc1, 0, 0, 0);
    int j0 = n0 + r, j1 = n0 + 16 + r;
    float bias0 = bih[j0] + bhh[j0];
    float bias1 = bih[j1] + bhh[j1];
    #pragma unroll
    for (int i = 0; i < 4; i++) {
        int row = m0 + q * 4 + i;
        int p0 = pos[2 * row], p1 = pos[2 * row + 1];
        float oh0 = Wih[(size_t)j0 * 532 + 512 + p0] + Wih[(size_t)j0 * 532 + 522 + p1];
        float oh1 = Wih[(size_t)j1 * 532 + 512 + p0] + Wih[(size_t)j1 * 532 + 522 + p1];
        gx[(size_t)row * 512 + j0] = acc0[i] + bias0 + oh0;
        gx[(size_t)row * 512 + j1] = acc1[i] + bias1 + oh1;
    }
}

// ---------------- LSTM: 32 independent blocks (one per batch element) ----------------
__global__ __launch_bounds__(512, 2) void lstm_kernel(
    const float* __restrict__ gx, const float* __restrict__ Whh,
    const int* __restrict__ done, const float* __restrict__ h0,
    const float* __restrict__ c0, ushort_t* __restrict__ hs,
    float* __restrict__ out)
{
    __shared__ __align__(16) float h_s[128];
    __shared__ float gates_s[512];
    int b = blockIdx.x, tid = threadIdx.x;
    int g = tid >> 7, j = tid & 127;

    float w[128];
    const float* wr = Whh + (size_t)(g * 128 + j) * 128;
    #pragma unroll
    for (int k = 0; k < 128; k += 4) {
        float4 v = *(const float4*)(wr + k);
        w[k] = v.x; w[k + 1] = v.y; w[k + 2] = v.z; w[k + 3] = v.w;
    }
    float h = h0[b * 128 + j];
    float c = c0[b * 128 + j];
    const float* gxb = gx + (size_t)b * 512;

    for (int t = 0; t < TT; t++) {
        float m = 1.0f - (float)done[t * 32 + b];
        c *= m;
        if (g == 0) h_s[j] = h * m;
        __syncthreads();
        float acc = 0.0f;
        #pragma unroll
        for (int k = 0; k < 128; k += 4) {
            float4 hv = *(const float4*)&h_s[k];
            acc = fmaf(w[k], hv.x, acc);
            acc = fmaf(w[k + 1], hv.y, acc);
            acc = fmaf(w[k + 2], hv.z, acc);
            acc = fmaf(w[k + 3], hv.w, acc);
        }
        acc += gxb[(size_t)t * 32 * 512 + (g << 7) + j];
        gates_s[(g << 7) + j] = acc;
        __syncthreads();
        float iv = sigmoid_f(gates_s[j]);
        float fv = sigmoid_f(gates_s[128 + j]);
        float gv = tanhf(gates_s[256 + j]);
        float ov = sigmoid_f(gates_s[384 + j]);
        c = fv * c + iv * gv;
        h = ov * tanhf(c);
        if (g == 0) hs[((size_t)t * 32 + b) * 128 + j] = f2bf(h);
    }
    if (g == 0) {
        out[12288 + b * 128 + j] = h;
        out[16384 + b * 128 + j] = c;
    }
}

// ---------------- heads: logits (2048x5), v (2048) ----------------
__global__ __launch_bounds__(256) void heads_kernel(
    const ushort_t* __restrict__ hs, const float* __restrict__ Wp,
    const float* __restrict__ bp, const float* __restrict__ Wv,
    const float* __restrict__ bv, float* __restrict__ out)
{
    int id = blockIdx.x * 256 + threadIdx.x;   // 12288 = 2048*6
    int n = id / 6, q = id % 6;
    const ushort_t* hrow = hs + (size_t)n * 128;
    if (q < 5) {
        float acc = bp[q];
        for (int k = 0; k < 128; k++) acc = fmaf(bf2f(hrow[k]), Wp[k * 5 + q], acc);
        out[n * 5 + q] = acc;
    } else {
        float acc = bv[0];
        for (int k = 0; k < 128; k++) acc = fmaf(bf2f(hrow[k]), Wv[k], acc);
        out[10240 + n] = acc;
    }
}

extern "C" void kernel_launch(void* const* d_in, const int* in_sizes, int n_in,
                              void* d_out, int out_size, void* d_ws, size_t ws_size,
                              hipStream_t stream) {
    const float* image = (const float*)d_in[0];
    const int*   pos   = (const int*)d_in[1];
    const int*   done  = (const int*)d_in[2];
    const float* h0    = (const float*)d_in[3];
    const float* c0    = (const float*)d_in[4];
    const float* W1    = (const float*)d_in[5];
    const float* b1    = (const float*)d_in[6];
    const float* W2    = (const float*)d_in[7];
    const float* b2    = (const float*)d_in[8];
    const float* W3    = (const float*)d_in[9];
    const float* b3    = (const float*)d_in[10];
    const float* Wfc   = (const float*)d_in[11];
    const float* bfc   = (const float*)d_in[12];
    const float* Wih   = (const float*)d_in[13];
    const float* Whh   = (const float*)d_in[14];
    const float* bih   = (const float*)d_in[15];
    const float* bhh   = (const float*)d_in[16];
    const float* Wp    = (const float*)d_in[17];
    const float* bp    = (const float*)d_in[18];
    const float* Wv    = (const float*)d_in[19];
    const float* bv    = (const float*)d_in[20];

    char* ws = (char*)d_ws;
    ushort_t* Wihb = (ushort_t*)(ws + 0);           //   524,288 B
    ushort_t* WfcT = (ushort_t*)(ws + 524288);      // 3,211,264 -> 3,735,552
    ushort_t* W1b  = (ushort_t*)(ws + 3735552);     //    16,384 -> 3,751,936
    ushort_t* W2b  = (ushort_t*)(ws + 3751936);     //    65,536 -> 3,817,472
    ushort_t* W3b  = (ushort_t*)(ws + 3817472);     //    73,728 -> 3,891,200
    ushort_t* out3 = (ushort_t*)(ws + 4194304);     // 12,845,056 -> 17,039,360
    ushort_t* feat = (ushort_t*)(ws + 17039360);    //  2,097,152 -> 19,136,512
    float*    gx   = (float*)(ws + 19136512);       //  4,194,304 -> 23,330,816
    ushort_t* hs   = (ushort_t*)(ws + 23330816);    //    524,288 -> 23,855,104

    float* out = (float*)d_out;

    prep_kernel<<<1024, 256, 0, stream>>>(Wih, Wihb);
    prep_convw_kernel<<<304, 256, 0, stream>>>(W1, W2, W3, W1b, W2b, W3b);
    wfct_kernel<<<392, 256, 0, stream>>>(Wfc, WfcT);
    convs_mfma<<<2048, 256, 0, stream>>>(image, W1b, b1, W2b, b2, W3b, b3, out3);
    fc_mfma_kernel<<<512, 256, 0, stream>>>(out3, WfcT, bfc, feat);
    gates_mfma_kernel<<<512, 256, 0, stream>>>(feat, Wihb, Wih, bih, bhh, pos, gx);
    lstm_kernel<<<32, 512, 0, stream>>>(gx, Whh, done, h0, c0, hs, out);
    heads_kernel<<<48, 256, 0, stream>>>(hs, Wp, bp, Wv, bv, out);
}

// Round 6
// 517.548 us; speedup vs baseline: 1.5353x; 1.1299x over previous
//
#include <hip/hip_runtime.h>

typedef unsigned short ushort_t;
typedef unsigned int uint_t;
typedef __attribute__((ext_vector_type(8))) short short8;
typedef __attribute__((ext_vector_type(4))) short short4v;
typedef __attribute__((ext_vector_type(4))) float floatx4;

__device__ __forceinline__ float bf2f(ushort_t u){
    union { uint_t i; float f; } c; c.i = ((uint_t)u) << 16; return c.f;
}
__device__ __forceinline__ ushort_t f2bf(float x){
    union { float f; uint_t i; } c; c.f = x;
    uint_t i = c.i;
    return (ushort_t)((i + 0x7fffu + ((i >> 16) & 1u)) >> 16);
}
// fast pack of 2 fp32 -> 2 bf16 (round-half-up): 2 adds + v_perm
__device__ __forceinline__ uint_t cvt2fast(float a, float b){
    union { float f; uint_t i; } ca, cb; ca.f = a; cb.f = b;
    uint_t ia = ca.i + 0x8000u, ib = cb.i + 0x8000u;
    return __builtin_amdgcn_perm(ib, ia, 0x07060302u);
}
__device__ __forceinline__ float relu_f(float x){ return fmaxf(x, 0.0f); }
__device__ __forceinline__ float sigmoid_f(float x){ return 1.0f / (1.0f + __expf(-x)); }

#define NT 2048
#define TT 64

// ---------------- prep: Wihb[j][k] = bf16(Wih[j][k]), k<512 ----------------
__global__ __launch_bounds__(256) void prep_kernel(
    const float* __restrict__ Wih, ushort_t* __restrict__ Wihb)
{
    int i = blockIdx.x * 256 + threadIdx.x;   // 262144
    int j = i >> 9, k = i & 511;
    Wihb[i] = f2bf(Wih[j * 532 + k]);
}

// ---------------- prep conv weights: W1b[8][32oc][32k], W2b[16][64oc][32ic], W3b[9][64oc][64ic] ----------------
__global__ __launch_bounds__(256) void prep_convw_kernel(
    const float* __restrict__ W1, const float* __restrict__ W2,
    const float* __restrict__ W3, ushort_t* __restrict__ W1b,
    ushort_t* __restrict__ W2b, ushort_t* __restrict__ W3b)
{
    int i = blockIdx.x * 256 + threadIdx.x;   // 77824 total
    if (i < 8192) {                           // W1b: k = kx*3+ic (24 real, pad 8 zeros)
        int ky = i >> 10, oc = (i >> 5) & 31, k = i & 31;
        float v = 0.0f;
        if (k < 24) { int kx = k / 3, ic = k % 3; v = W1[((ky * 8 + kx) * 3 + ic) * 32 + oc]; }
        W1b[i] = f2bf(v);
        return;
    }
    i -= 8192;
    if (i < 32768) {                          // W2b[kk][oc][ic]
        int kk = i >> 11, oc = (i >> 5) & 63, ic = i & 31;
        W2b[i] = f2bf(W2[(kk * 32 + ic) * 64 + oc]);
        return;
    }
    i -= 32768;
    if (i < 36864) {                          // W3b[p][oc][ic]
        int p = i >> 12, oc = (i >> 6) & 63, ic = i & 63;
        W3b[i] = f2bf(W3[(p * 64 + ic) * 64 + oc]);
    }
}

// ---------------- wfct: Wfc[3136][512] f32 -> WfcT[512][3136] bf16 ----------------
__global__ __launch_bounds__(256) void wfct_kernel(
    const float* __restrict__ Wfc, ushort_t* __restrict__ WfcT)
{
    __shared__ ushort_t t_s[64][65];
    int kb = blockIdx.x % 49, jb = blockIdx.x / 49;   // 49*8 blocks
    int k0 = kb * 64, j0 = jb * 64;
    int jj = threadIdx.x & 63, i4 = threadIdx.x >> 6;
    for (int rr = i4; rr < 64; rr += 4)
        t_s[rr][jj] = f2bf(Wfc[(size_t)(k0 + rr) * 512 + j0 + jj]);
    __syncthreads();
    for (int rr = i4; rr < 64; rr += 4)
        WfcT[(size_t)(j0 + rr) * 3136 + k0 + jj] = t_s[jj][rr];
}

// ---------------- fused convs via MFMA, block per sample ----------------
// 256 threads (4 waves), R0 compute structure (shared-A conv1, single-pass
// conv2/conv3) + planar LDS (conflict-free frag reads) + conv1 2-tile ILP.
// Registers bind occupancy at ~4 waves/SIMD (AGPR-inclusive ~108); the lever
// here is per-wave ILP, not occupancy. launch_bounds(256,4): cap 128 (the
// only empirically spill-free regime: R2 cap64 / R4 cap85 both spilled).
// LDS (aliased c1/c2, 25,728 B):
//   c1: chunk = (x&1)*4 + oct*2 + (ch>>3), addr = chunk*1608 + (y*10+x/2)*8 + (ch&7)
//   c2: kc*656 + px*8 + (ch&7)   [written after an extra barrier]
// Chunk strides 1608/656 halves keep q-group reads on disjoint bank quads.
__global__ __launch_bounds__(256, 4) void convs_mfma(
    const float* __restrict__ img,
    const ushort_t* __restrict__ W1b, const float* __restrict__ b1,
    const ushort_t* __restrict__ W2b, const float* __restrict__ b2,
    const ushort_t* __restrict__ W3b, const float* __restrict__ b3,
    ushort_t* __restrict__ out3)
{
    __shared__ __align__(16) ushort_t smem[12864];   // 25,728 B

    int n = blockIdx.x, tid = threadIdx.x;
    int w = tid >> 6, lane = tid & 63;
    int r = lane & 15, q = lane >> 4;

    // ---- conv1: 20x20x32, k=8 s=4; K=32 (kx*3+ic, rows 24..31 zero) ----
    // wave = px-phase; BOTH 16-oc tiles from one A-fragment; two pixel-tiles
    // (t, t+4) in flight for 2x independent global-load chains.
    {
        short8 bf0[8], bf1[8];
        #pragma unroll
        for (int ky = 0; ky < 8; ky++) {
            bf0[ky] = *(const short8*)(W1b + (ky * 32 +      r) * 32 + q * 8);
            bf1[ky] = *(const short8*)(W1b + (ky * 32 + 16 + r) * 32 + q * 8);
        }
        float bb0 = b1[r], bb1 = b1[16 + r];
        const float* abase = img + (size_t)n * 21168;

        int t = w;
        for (; t + 4 < 25; t += 8) {
            int pxaA = t * 16 + r, pxaB = (t + 4) * 16 + r;
            int oyA = pxaA / 20, oxA = pxaA % 20;
            int oyB = pxaB / 20, oxB = pxaB % 20;
            floatx4 aA0 = {0.f,0.f,0.f,0.f}, aA1 = {0.f,0.f,0.f,0.f};
            floatx4 aB0 = {0.f,0.f,0.f,0.f}, aB1 = {0.f,0.f,0.f,0.f};
            #pragma unroll
            for (int ky = 0; ky < 8; ky++) {
                short8 a = {0,0,0,0,0,0,0,0};
                short8 b = {0,0,0,0,0,0,0,0};
                if (q < 3) {
                    const float* pA = abase + ((oyA * 4 + ky) * 84 + oxA * 4) * 3 + q * 8;
                    const float* pB = abase + ((oyB * 4 + ky) * 84 + oxB * 4) * 3 + q * 8;
                    float4 fA0 = *(const float4*)pA;
                    float4 fA1 = *(const float4*)(pA + 4);
                    float4 fB0 = *(const float4*)pB;
                    float4 fB1 = *(const float4*)(pB + 4);
                    union { uint_t u[4]; short8 s; } pk;
                    pk.u[0] = cvt2fast(fA0.x, fA0.y);
                    pk.u[1] = cvt2fast(fA0.z, fA0.w);
                    pk.u[2] = cvt2fast(fA1.x, fA1.y);
                    pk.u[3] = cvt2fast(fA1.z, fA1.w);
                    a = pk.s;
                    pk.u[0] = cvt2fast(fB0.x, fB0.y);
                    pk.u[1] = cvt2fast(fB0.z, fB0.w);
                    pk.u[2] = cvt2fast(fB1.x, fB1.y);
                    pk.u[3] = cvt2fast(fB1.z, fB1.w);
                    b = pk.s;
                }
                aA0 = __builtin_amdgcn_mfma_f32_16x16x32_bf16(a, bf0[ky], aA0, 0, 0, 0);
                aA1 = __builtin_amdgcn_mfma_f32_16x16x32_bf16(a, bf1[ky], aA1, 0, 0, 0);
                aB0 = __builtin_amdgcn_mfma_f32_16x16x32_bf16(b, bf0[ky], aB0, 0, 0, 0);
                aB1 = __builtin_amdgcn_mfma_f32_16x16x32_bf16(b, bf1[ky], aB1, 0, 0, 0);
            }
            #pragma unroll
            for (int pair = 0; pair < 2; pair++) {
                int tt = t + pair * 4;
                floatx4 acc0 = pair ? aB0 : aA0;
                floatx4 acc1 = pair ? aB1 : aA1;
                int pxs = tt * 16 + q * 4;
                #pragma unroll
                for (int i = 0; i < 4; i++) {
                    int px = pxs + i;
                    int y = px / 20, x = px % 20;
                    int base = (x & 1) * 4 * 1608 + (y * 10 + (x >> 1)) * 8 + (r & 7);
                    smem[base + ((r >> 3)    ) * 1608] = f2bf(relu_f(acc0[i] + bb0));
                    smem[base + (2 + (r >> 3)) * 1608] = f2bf(relu_f(acc1[i] + bb1));
                }
            }
        }
        if (t < 25) {   // leftover (wave 0: t=24)
            int pxa = t * 16 + r;
            int oy = pxa / 20, ox = pxa % 20;
            floatx4 acc0 = {0.f,0.f,0.f,0.f}, acc1 = {0.f,0.f,0.f,0.f};
            #pragma unroll
            for (int ky = 0; ky < 8; ky++) {
                short8 a = {0,0,0,0,0,0,0,0};
                if (q < 3) {
                    const float* p = abase + ((oy * 4 + ky) * 84 + ox * 4) * 3 + q * 8;
                    float4 f0 = *(const float4*)p;
                    float4 f1 = *(const float4*)(p + 4);
                    union { uint_t u[4]; short8 s; } pk;
                    pk.u[0] = cvt2fast(f0.x, f0.y);
                    pk.u[1] = cvt2fast(f0.z, f0.w);
                    pk.u[2] = cvt2fast(f1.x, f1.y);
                    pk.u[3] = cvt2fast(f1.z, f1.w);
                    a = pk.s;
                }
                acc0 = __builtin_amdgcn_mfma_f32_16x16x32_bf16(a, bf0[ky], acc0, 0, 0, 0);
                acc1 = __builtin_amdgcn_mfma_f32_16x16x32_bf16(a, bf1[ky], acc1, 0, 0, 0);
            }
            int pxs = t * 16 + q * 4;
            #pragma unroll
            for (int i = 0; i < 4; i++) {
                int px = pxs + i;
                int y = px / 20, x = px % 20;
                int base = (x & 1) * 4 * 1608 + (y * 10 + (x >> 1)) * 8 + (r & 7);
                smem[base + ((r >> 3)    ) * 1608] = f2bf(relu_f(acc0[i] + bb0));
                smem[base + (2 + (r >> 3)) * 1608] = f2bf(relu_f(acc1[i] + bb1));
            }
        }
    }
    __syncthreads();

    // ---- conv2: 9x9x64, k=4 s=2; wave = oc-tile; single-pass 16 frags ----
    float accv[6][4];
    {
        int oct = w;
        short8 bfr[16];
        #pragma unroll
        for (int kk = 0; kk < 16; kk++)
            bfr[kk] = *(const short8*)(W2b + (kk * 64 + oct * 16 + r) * 32 + q * 8);
        #pragma unroll
        for (int t = 0; t < 6; t++) {
            int pxa = min(t * 16 + r, 80);
            int oy = pxa / 9, ox = pxa % 9;
            floatx4 acc = {0.f, 0.f, 0.f, 0.f};
            #pragma unroll
            for (int ky = 0; ky < 4; ky++) {
                #pragma unroll
                for (int kxh = 0; kxh < 2; kxh++) {   // kx = 2*kxh (even plane), 2*kxh+1 (odd)
                    int pos = (oy * 2 + ky) * 10 + ox + kxh;
                    const ushort_t* pe = smem + q * 1608 + pos * 8;
                    short8 ae = *(const short8*)pe;
                    short8 ao = *(const short8*)(pe + 4 * 1608);
                    acc = __builtin_amdgcn_mfma_f32_16x16x32_bf16(ae, bfr[ky * 4 + kxh * 2],     acc, 0, 0, 0);
                    acc = __builtin_amdgcn_mfma_f32_16x16x32_bf16(ao, bfr[ky * 4 + kxh * 2 + 1], acc, 0, 0, 0);
                }
            }
            #pragma unroll
            for (int i = 0; i < 4; i++) accv[t][i] = acc[i];
        }
    }
    __syncthreads();
    // store c2 into the re-used LDS region
    {
        int oct = w;
        float bb = b2[oct * 16 + r];
        int kcb = (oct * 2 + (r >> 3)) * 656 + (r & 7);
        #pragma unroll
        for (int t = 0; t < 6; t++) {
            #pragma unroll
            for (int i = 0; i < 4; i++) {
                int px = t * 16 + q * 4 + i;
                if (px < 81)
                    smem[kcb + px * 8] = f2bf(relu_f(accv[t][i] + bb));
            }
        }
    }
    __syncthreads();

    // ---- conv3: 7x7x64, k=3 s=1; wave = oc-tile; single-pass 18 frags ----
    {
        int oct = w;
        short8 bfr[18];
        #pragma unroll
        for (int p = 0; p < 9; p++) {
            #pragma unroll
            for (int h = 0; h < 2; h++)
                bfr[p * 2 + h] = *(const short8*)(W3b + (p * 64 + oct * 16 + r) * 64 + h * 32 + q * 8);
        }
        float bb = b3[oct * 16 + r];
        for (int t = 0; t < 4; t++) {
            int pxa = min(t * 16 + r, 48);
            int oy = pxa / 7, ox = pxa % 7;
            floatx4 acc = {0.f, 0.f, 0.f, 0.f};
            #pragma unroll
            for (int ky = 0; ky < 3; ky++) {
                #pragma unroll
                for (int kx = 0; kx < 3; kx++) {
                    int qin = (oy + ky) * 9 + ox + kx;
                    const ushort_t* p0 = smem + q * 656 + qin * 8;
                    short8 a0 = *(const short8*)p0;
                    short8 a1 = *(const short8*)(p0 + 4 * 656);
                    acc = __builtin_amdgcn_mfma_f32_16x16x32_bf16(a0, bfr[(ky * 3 + kx) * 2],     acc, 0, 0, 0);
                    acc = __builtin_amdgcn_mfma_f32_16x16x32_bf16(a1, bfr[(ky * 3 + kx) * 2 + 1], acc, 0, 0, 0);
                }
            }
            #pragma unroll
            for (int i = 0; i < 4; i++) {
                int px = t * 16 + q * 4 + i;
                if (px < 49)
                    out3[(size_t)n * 3136 + px * 64 + oct * 16 + r] = f2bf(relu_f(acc[i] + bb));
            }
        }
    }
}

// ---------------- FC via MFMA: feat[2048][512] = relu(out3 @ Wfc + bfc) ----------------
__global__ __launch_bounds__(256) void fc_mfma_kernel(
    const ushort_t* __restrict__ A, const ushort_t* __restrict__ BT,
    const float* __restrict__ bfc, ushort_t* __restrict__ feat)
{
    int mb = blockIdx.x & 63, nb = blockIdx.x >> 6;   // 64 x 8
    int tid = threadIdx.x;
    int w = tid >> 6, lane = tid & 63;
    int r = lane & 15, q = lane >> 4;
    int m0 = mb * 32 + (w & 1) * 16;
    int n0 = nb * 64 + (w >> 1) * 32;
    const ushort_t* arow  = A  + (size_t)(m0 + r) * 3136 + q * 8;
    const ushort_t* brow0 = BT + (size_t)(n0 + r) * 3136 + q * 8;
    const ushort_t* brow1 = BT + (size_t)(n0 + 16 + r) * 3136 + q * 8;
    floatx4 acc0 = {0.f, 0.f, 0.f, 0.f}, acc1 = {0.f, 0.f, 0.f, 0.f};
    short8 a  = *(const short8*)arow;
    short8 b0 = *(const short8*)brow0;
    short8 b1 = *(const short8*)brow1;
    for (int kk = 1; kk < 98; kk++) {
        short8 an  = *(const short8*)(arow  + kk * 32);
        short8 b0n = *(const short8*)(brow0 + kk * 32);
        short8 b1n = *(const short8*)(brow1 + kk * 32);
        acc0 = __builtin_amdgcn_mfma_f32_16x16x32_bf16(a, b0, acc0, 0, 0, 0);
        acc1 = __builtin_amdgcn_mfma_f32_16x16x32_bf16(a, b1, acc1, 0, 0, 0);
        a = an; b0 = b0n; b1 = b1n;
    }
    acc0 = __builtin_amdgcn_mfma_f32_16x16x32_bf16(a, b0, acc0, 0, 0, 0);
    acc1 = __builtin_amdgcn_mfma_f32_16x16x32_bf16(a, b1, acc1, 0, 0, 0);
    int c0 = n0 + r, c1 = n0 + 16 + r;
    float bb0 = bfc[c0], bb1 = bfc[c1];
    #pragma unroll
    for (int i = 0; i < 4; i++) {
        int row = m0 + q * 4 + i;
        feat[(size_t)row * 512 + c0] = f2bf(relu_f(acc0[i] + bb0));
        feat[(size_t)row * 512 + c1] = f2bf(relu_f(acc1[i] + bb1));
    }
}

// ---------------- gates via MFMA: gx[2048][512] = feat @ Wih[:,:512]^T + onehot + bias ----------------
__global__ __launch_bounds__(256) void gates_mfma_kernel(
    const ushort_t* __restrict__ A, const ushort_t* __restrict__ Wihb,
    const float* __restrict__ Wih, const float* __restrict__ bih,
    const float* __restrict__ bhh, const int* __restrict__ pos,
    float* __restrict__ gx)
{
    int mb = blockIdx.x & 63, nb = blockIdx.x >> 6;   // 64 x 8
    int tid = threadIdx.x;
    int w = tid >> 6, lane = tid & 63;
    int r = lane & 15, q = lane >> 4;
    int m0 = mb * 32 + (w & 1) * 16;
    int n0 = nb * 64 + (w >> 1) * 32;
    const ushort_t* arow  = A    + (size_t)(m0 + r) * 512 + q * 8;
    const ushort_t* brow0 = Wihb + (size_t)(n0 + r) * 512 + q * 8;
    const ushort_t* brow1 = Wihb + (size_t)(n0 + 16 + r) * 512 + q * 8;
    floatx4 acc0 = {0.f, 0.f, 0.f, 0.f}, acc1 = {0.f, 0.f, 0.f, 0.f};
    short8 a  = *(const short8*)arow;
    short8 b0 = *(const short8*)brow0;
    short8 b1 = *(const short8*)brow1;
    for (int kk = 1; kk < 16; kk++) {
        short8 an  = *(const short8*)(arow  + kk * 32);
        short8 b0n = *(const short8*)(brow0 + kk * 32);
        short8 b1n = *(const short8*)(brow1 + kk * 32);
        acc0 = __builtin_amdgcn_mfma_f32_16x16x32_bf16(a, b0, acc0, 0, 0, 0);
        acc1 = __builtin_amdgcn_mfma_f32_16x16x32_bf16(a, b1, acc1, 0, 0, 0);
        a = an; b0 = b0n; b1 = b1n;
    }
    acc0 = __builtin_amdgcn_mfma_f32_16x16x32_bf16(a, b0, acc0, 0, 0, 0);
    acc1 = __builtin_amdgcn_mfma_f32_16x16x32_bf16(a, b1, acc1, 0, 0, 0);
    int j0 = n0 + r, j1 = n0 + 16 + r;
    float bias0 = bih[j0] + bhh[j0];
    float bias1 = bih[j1] + bhh[j1];
    #pragma unroll
    for (int i = 0; i < 4; i++) {
        int row = m0 + q * 4 + i;
        int p0 = pos[2 * row], p1 = pos[2 * row + 1];
        float oh0 = Wih[(size_t)j0 * 532 + 512 + p0] + Wih[(size_t)j0 * 532 + 522 + p1];
        float oh1 = Wih[(size_t)j1 * 532 + 512 + p0] + Wih[(size_t)j1 * 532 + 522 + p1];
        gx[(size_t)row * 512 + j0] = acc0[i] + bias0 + oh0;
        gx[(size_t)row * 512 + j1] = acc1[i] + bias1 + oh1;
    }
}

// ---------------- LSTM: 32 independent blocks (one per batch element) ----------------
__global__ __launch_bounds__(512, 2) void lstm_kernel(
    const float* __restrict__ gx, const float* __restrict__ Whh,
    const int* __restrict__ done, const float* __restrict__ h0,
    const float* __restrict__ c0, ushort_t* __restrict__ hs,
    float* __restrict__ out)
{
    __shared__ __align__(16) float h_s[128];
    __shared__ float gates_s[512];
    int b = blockIdx.x, tid = threadIdx.x;
    int g = tid >> 7, j = tid & 127;

    float w[128];
    const float* wr = Whh + (size_t)(g * 128 + j) * 128;
    #pragma unroll
    for (int k = 0; k < 128; k += 4) {
        float4 v = *(const float4*)(wr + k);
        w[k] = v.x; w[k + 1] = v.y; w[k + 2] = v.z; w[k + 3] = v.w;
    }
    float h = h0[b * 128 + j];
    float c = c0[b * 128 + j];
    const float* gxb = gx + (size_t)b * 512;

    for (int t = 0; t < TT; t++) {
        float m = 1.0f - (float)done[t * 32 + b];
        c *= m;
        if (g == 0) h_s[j] = h * m;
        __syncthreads();
        float acc = 0.0f;
        #pragma unroll
        for (int k = 0; k < 128; k += 4) {
            float4 hv = *(const float4*)&h_s[k];
            acc = fmaf(w[k], hv.x, acc);
            acc = fmaf(w[k + 1], hv.y, acc);
            acc = fmaf(w[k + 2], hv.z, acc);
            acc = fmaf(w[k + 3], hv.w, acc);
        }
        acc += gxb[(size_t)t * 32 * 512 + (g << 7) + j];
        gates_s[(g << 7) + j] = acc;
        __syncthreads();
        float iv = sigmoid_f(gates_s[j]);
        float fv = sigmoid_f(gates_s[128 + j]);
        float gv = tanhf(gates_s[256 + j]);
        float ov = sigmoid_f(gates_s[384 + j]);
        c = fv * c + iv * gv;
        h = ov * tanhf(c);
        if (g == 0) hs[((size_t)t * 32 + b) * 128 + j] = f2bf(h);
    }
    if (g == 0) {
        out[12288 + b * 128 + j] = h;
        out[16384 + b * 128 + j] = c;
    }
}

// ---------------- heads: logits (2048x5), v (2048) ----------------
__global__ __launch_bounds__(256) void heads_kernel(
    const ushort_t* __restrict__ hs, const float* __restrict__ Wp,
    const float* __restrict__ bp, const float* __restrict__ Wv,
    const float* __restrict__ bv, float* __restrict__ out)
{
    int id = blockIdx.x * 256 + threadIdx.x;   // 12288 = 2048*6
    int n = id / 6, q = id % 6;
    const ushort_t* hrow = hs + (size_t)n * 128;
    if (q < 5) {
        float acc = bp[q];
        for (int k = 0; k < 128; k++) acc = fmaf(bf2f(hrow[k]), Wp[k * 5 + q], acc);
        out[n * 5 + q] = acc;
    } else {
        float acc = bv[0];
        for (int k = 0; k < 128; k++) acc = fmaf(bf2f(hrow[k]), Wv[k], acc);
        out[10240 + n] = acc;
    }
}

extern "C" void kernel_launch(void* const* d_in, const int* in_sizes, int n_in,
                              void* d_out, int out_size, void* d_ws, size_t ws_size,
                              hipStream_t stream) {
    const float* image = (const float*)d_in[0];
    const int*   pos   = (const int*)d_in[1];
    const int*   done  = (const int*)d_in[2];
    const float* h0    = (const float*)d_in[3];
    const float* c0    = (const float*)d_in[4];
    const float* W1    = (const float*)d_in[5];
    const float* b1    = (const float*)d_in[6];
    const float* W2    = (const float*)d_in[7];
    const float* b2    = (const float*)d_in[8];
    const float* W3    = (const float*)d_in[9];
    const float* b3    = (const float*)d_in[10];
    const float* Wfc   = (const float*)d_in[11];
    const float* bfc   = (const float*)d_in[12];
    const float* Wih   = (const float*)d_in[13];
    const float* Whh   = (const float*)d_in[14];
    const float* bih   = (const float*)d_in[15];
    const float* bhh   = (const float*)d_in[16];
    const float* Wp    = (const float*)d_in[17];
    const float* bp    = (const float*)d_in[18];
    const float* Wv    = (const float*)d_in[19];
    const float* bv    = (const float*)d_in[20];

    char* ws = (char*)d_ws;
    ushort_t* Wihb = (ushort_t*)(ws + 0);           //   524,288 B
    ushort_t* WfcT = (ushort_t*)(ws + 524288);      // 3,211,264 -> 3,735,552
    ushort_t* W1b  = (ushort_t*)(ws + 3735552);     //    16,384 -> 3,751,936
    ushort_t* W2b  = (ushort_t*)(ws + 3751936);     //    65,536 -> 3,817,472
    ushort_t* W3b  = (ushort_t*)(ws + 3817472);     //    73,728 -> 3,891,200
    ushort_t* out3 = (ushort_t*)(ws + 4194304);     // 12,845,056 -> 17,039,360
    ushort_t* feat = (ushort_t*)(ws + 17039360);    //  2,097,152 -> 19,136,512
    float*    gx   = (float*)(ws + 19136512);       //  4,194,304 -> 23,330,816
    ushort_t* hs   = (ushort_t*)(ws + 23330816);    //    524,288 -> 23,855,104

    float* out = (float*)d_out;

    prep_kernel<<<1024, 256, 0, stream>>>(Wih, Wihb);
    prep_convw_kernel<<<304, 256, 0, stream>>>(W1, W2, W3, W1b, W2b, W3b);
    wfct_kernel<<<392, 256, 0, stream>>>(Wfc, WfcT);
    convs_mfma<<<2048, 256, 0, stream>>>(image, W1b, b1, W2b, b2, W3b, b3, out3);
    fc_mfma_kernel<<<512, 256, 0, stream>>>(out3, WfcT, bfc, feat);
    gates_mfma_kernel<<<512, 256, 0, stream>>>(feat, Wihb, Wih, bih, bhh, pos, gx);
    lstm_kernel<<<32, 512, 0, stream>>>(gx, Whh, done, h0, c0, hs, out);
    heads_kernel<<<48, 256, 0, stream>>>(hs, Wp, bp, Wv, bv, out);
}